// Round 1
// baseline (172.525 us; speedup 1.0000x reference)
//
#include <hip/hip_runtime.h>
#include <hip/hip_bf16.h>
#include <math.h>

#define B_DIM 8192
#define IN_F  1024
#define OUT_F 1024
#define NSLAB 5
#define K_DIM (IN_F * (1 + NSLAB))   // 6144

#define BM 128
#define BN 128
#define BK 32

typedef unsigned short u16;
typedef __attribute__((ext_vector_type(8))) short bf16x8;
typedef __attribute__((ext_vector_type(4))) float f32x4;
typedef __attribute__((ext_vector_type(4))) unsigned short u16x4;

#define GLOBAL_AS __attribute__((address_space(1)))
#define LDS_AS    __attribute__((address_space(3)))

__device__ __forceinline__ void gload16(const void* g, void* l) {
    __builtin_amdgcn_global_load_lds((const GLOBAL_AS unsigned int*)g,
                                     (LDS_AS unsigned int*)l, 16, 0, 0);
}

__device__ __forceinline__ u16 f2bf(float v) {
    unsigned int u = __float_as_uint(v);
    return (u16)((u + 0x7FFFu + ((u >> 16) & 1u)) >> 16);
}

// ---------------------------------------------------------------------------
// pack_A: A[b, 0:1024]          = bf16(x[b,i])
//         A[b, 1024 + g*1024+i] = (interval(tanh(x[b,i])) == g) ? 1.0bf16 : 0
// Interval classification done in x-space: rounded_tanh(x) >= grid[k]
//   <=>  x > atanh(midpoint(grid[k], prev_float(grid[k])))   (double precision)
// ---------------------------------------------------------------------------
__global__ __launch_bounds__(256) void pack_A_kernel(
    const float* __restrict__ x, const float* __restrict__ grid,
    u16* __restrict__ A)
{
    __shared__ double thr[5];
    if (threadIdx.x == 0) {
        #pragma unroll
        for (int k = 0; k < 4; ++k) {
            float gv = grid[k + 1];                 // -0.6, -0.2, 0.2, 0.6
            float below = nextafterf(gv, -2.0f);
            double mid = 0.5 * ((double)gv + (double)below);
            thr[k] = atanh(mid);
        }
        {
            float gv = grid[5];                     // 1.0
            float below = nextafterf(gv, 0.0f);
            double mid = 0.5 * ((double)gv + (double)below);
            thr[4] = atanh(mid);                    // ~9.0109: tanh rounds to 1.0f
        }
    }
    __syncthreads();
    double t1 = thr[0], t2 = thr[1], t3 = thr[2], t4 = thr[3], t5 = thr[4];

    int gid = blockIdx.x * 256 + threadIdx.x;       // 0 .. B*IN/4 - 1
    int b   = gid >> 8;                             // 256 float4-chunks per row
    int i0  = (gid & 255) << 2;

    float4 xv = *(const float4*)(x + (size_t)b * IN_F + i0);
    float xs[4] = {xv.x, xv.y, xv.z, xv.w};

    u16 xb[4];
    int gi[4];
    #pragma unroll
    for (int j = 0; j < 4; ++j) {
        float v = xs[j];
        xb[j] = f2bf(v);
        double xd = (double)v;
        int g = (xd > t1) + (xd > t2) + (xd > t3) + (xd > t4);
        if (xd > t5) g = -1;                        // xn == 1.0f: no interval
        gi[j] = g;
    }

    size_t rowbase = (size_t)b * K_DIM;
    u16x4 s0; s0[0]=xb[0]; s0[1]=xb[1]; s0[2]=xb[2]; s0[3]=xb[3];
    *(u16x4*)(A + rowbase + i0) = s0;

    #pragma unroll
    for (int g = 0; g < NSLAB; ++g) {
        u16x4 oh;
        oh[0] = (gi[0] == g) ? (u16)0x3F80 : (u16)0;
        oh[1] = (gi[1] == g) ? (u16)0x3F80 : (u16)0;
        oh[2] = (gi[2] == g) ? (u16)0x3F80 : (u16)0;
        oh[3] = (gi[3] == g) ? (u16)0x3F80 : (u16)0;
        *(u16x4*)(A + rowbase + IN_F + (size_t)g * IN_F + i0) = oh;
    }
}

// ---------------------------------------------------------------------------
// pack_B: Bm[o, 0:1024]           = bf16(bw[o,i])
//         Bm[o, 1024 + g*1024+i]  = bf16(sw[o,i,g]),  g < 5   (chs 5..7 unused)
// ---------------------------------------------------------------------------
__global__ __launch_bounds__(256) void pack_B_kernel(
    const float* __restrict__ sw, const float* __restrict__ bw,
    u16* __restrict__ Bm)
{
    int gid = blockIdx.x * 256 + threadIdx.x;       // 0 .. OUT*IN/4 - 1
    int o   = gid >> 8;
    int i0  = (gid & 255) << 2;

    float4 bv = *(const float4*)(bw + (size_t)o * IN_F + i0);
    float bs[4] = {bv.x, bv.y, bv.z, bv.w};

    size_t rowbase = (size_t)o * K_DIM;
    u16x4 s0; s0[0]=f2bf(bs[0]); s0[1]=f2bf(bs[1]); s0[2]=f2bf(bs[2]); s0[3]=f2bf(bs[3]);
    *(u16x4*)(Bm + rowbase + i0) = s0;

    float s[4][5];
    #pragma unroll
    for (int j = 0; j < 4; ++j) {
        const float4* p = (const float4*)(sw + ((size_t)o * IN_F + i0 + j) * 8);
        float4 lo = p[0];
        float4 hi = p[1];
        s[j][0]=lo.x; s[j][1]=lo.y; s[j][2]=lo.z; s[j][3]=lo.w; s[j][4]=hi.x;
    }
    #pragma unroll
    for (int g = 0; g < NSLAB; ++g) {
        u16x4 v;
        v[0]=f2bf(s[0][g]); v[1]=f2bf(s[1][g]); v[2]=f2bf(s[2][g]); v[3]=f2bf(s[3][g]);
        *(u16x4*)(Bm + rowbase + IN_F + (size_t)g * IN_F + i0) = v;
    }
}

// ---------------------------------------------------------------------------
// GEMM: C[M,N] f32 = A[M,K] bf16 @ Bm[N,K]^T bf16   (m97 structure, 128x128x32)
// 256 threads = 4 waves in 2x2 grid; each wave 64x64 out = 4x4 frags 16x16.
// ---------------------------------------------------------------------------
__global__ __launch_bounds__(256) void gemm_kernel(
    const u16* __restrict__ A, const u16* __restrict__ Bm,
    float* __restrict__ C)
{
    __shared__ __align__(16) u16 As[BM * BK];       // 8 KiB
    __shared__ __align__(16) u16 Bs[BN * BK];       // 8 KiB

    int tid = threadIdx.x;
    int bid = blockIdx.x;                           // 0..511 (grid 512 = 64x8)

    // XCD swizzle: each XCD gets an 8x8 supertile of output tiles.
    int xcd  = bid & 7;
    int slot = bid >> 3;
    int tile = xcd * 64 + slot;
    int brow = tile >> 3;                           // 0..63
    int bcol = tile & 7;                            // 0..7

    int lane = tid & 63;
    int w    = tid >> 6;
    int wr   = w >> 1;                              // wave row 0..1
    int wc   = w & 1;                               // wave col 0..1

    // staging: 8 KiB tile = 256 threads * 2 chunks * 16 B
    int off0 = tid * 16;
    int off1 = off0 + 4096;
    int r0 = off0 >> 6, cb0 = off0 & 63;            // 64 B per LDS row (32 bf16)
    int r1 = off1 >> 6, cb1 = off1 & 63;

    const char* Abase = (const char*)(A  + (size_t)(brow * BM) * K_DIM);
    const char* Bbase = (const char*)(Bm + (size_t)(bcol * BN) * K_DIM);
    const size_t rstride = (size_t)K_DIM * 2;       // global row stride in bytes

    // fragment addressing: lane holds row (lane&15), k = (lane>>4)*8 .. +7
    int fr = lane & 15;
    int fk = (lane >> 4) << 3;
    int aoff = (wr * 64 + fr) * BK + fk;
    int boff = (wc * 64 + fr) * BK + fk;

    f32x4 acc[4][4];
    #pragma unroll
    for (int m = 0; m < 4; ++m)
        #pragma unroll
        for (int n = 0; n < 4; ++n)
            #pragma unroll
            for (int j = 0; j < 4; ++j)
                acc[m][n][j] = 0.0f;

    for (int kt = 0; kt < K_DIM / BK; ++kt) {
        size_t k0b = (size_t)kt * (BK * 2);
        __syncthreads();                            // prev iter's ds_reads done
        gload16(Abase + (size_t)r0 * rstride + k0b + cb0, (char*)As + off0);
        gload16(Abase + (size_t)r1 * rstride + k0b + cb1, (char*)As + off1);
        gload16(Bbase + (size_t)r0 * rstride + k0b + cb0, (char*)Bs + off0);
        gload16(Bbase + (size_t)r1 * rstride + k0b + cb1, (char*)Bs + off1);
        __syncthreads();                            // vmcnt(0) drained by compiler

        bf16x8 af[4], bf[4];
        #pragma unroll
        for (int m = 0; m < 4; ++m)
            af[m] = *(const bf16x8*)(As + aoff + m * 16 * BK);
        #pragma unroll
        for (int n = 0; n < 4; ++n)
            bf[n] = *(const bf16x8*)(Bs + boff + n * 16 * BK);

        #pragma unroll
        for (int m = 0; m < 4; ++m)
            #pragma unroll
            for (int n = 0; n < 4; ++n)
                acc[m][n] = __builtin_amdgcn_mfma_f32_16x16x32_bf16(
                    af[m], bf[n], acc[m][n], 0, 0, 0);
    }

    // epilogue: C/D layout col = lane&15, row = (lane>>4)*4 + reg
    int crow0 = brow * BM + wr * 64 + ((lane >> 4) << 2);
    int ccol0 = bcol * BN + wc * 64 + (lane & 15);
    #pragma unroll
    for (int m = 0; m < 4; ++m)
        #pragma unroll
        for (int j = 0; j < 4; ++j) {
            size_t r = (size_t)(crow0 + m * 16 + j);
            float* cp = C + r * OUT_F + ccol0;
            #pragma unroll
            for (int n = 0; n < 4; ++n)
                cp[n * 16] = acc[m][n][j];
        }
}

// Fallback signal if workspace is too small: absmax will read ~12345.
__global__ void sentinel_kernel(float* out, int n) {
    int i = blockIdx.x * 256 + threadIdx.x;
    if (i < n) out[i] = (i == 0) ? 12345.0f : 0.0f;
}

extern "C" void kernel_launch(void* const* d_in, const int* in_sizes, int n_in,
                              void* d_out, int out_size, void* d_ws, size_t ws_size,
                              hipStream_t stream) {
    const float* x    = (const float*)d_in[0];
    const float* sw   = (const float*)d_in[1];
    const float* bw   = (const float*)d_in[2];
    const float* grid = (const float*)d_in[3];
    float* out = (float*)d_out;

    const size_t A_bytes = (size_t)B_DIM * K_DIM * 2;   // 100,663,296
    const size_t B_bytes = (size_t)OUT_F * K_DIM * 2;   //  12,582,912
    if (ws_size < A_bytes + B_bytes) {
        sentinel_kernel<<<(out_size + 255) / 256, 256, 0, stream>>>(out, out_size);
        return;
    }

    u16* Aexp = (u16*)d_ws;
    u16* Bm   = (u16*)((char*)d_ws + A_bytes);

    pack_A_kernel<<<B_DIM * IN_F / 1024, 256, 0, stream>>>(x, grid, Aexp);
    pack_B_kernel<<<OUT_F * IN_F / 1024, 256, 0, stream>>>(sw, bw, Bm);
    gemm_kernel<<<(B_DIM / BM) * (OUT_F / BN), 256, 0, stream>>>(Aexp, Bm, out);
}

// Round 2
// 154.141 us; speedup vs baseline: 1.1193x; 1.1193x over previous
//
#include <hip/hip_runtime.h>
#include <hip/hip_bf16.h>
#include <math.h>

#define B_DIM 8192
#define IN_F  1024
#define OUT_F 1024
#define NSLAB 5
#define K_DIM (IN_F * (1 + NSLAB))   // 6144
#define NKT   (K_DIM / 64)           // 96 K-tiles of 64
#define TILE_BYTES 16384             // one 128x64 bf16 tile image

typedef unsigned short u16;
typedef __attribute__((ext_vector_type(8))) short bf16x8;
typedef __attribute__((ext_vector_type(8))) unsigned short u16x8;
typedef __attribute__((ext_vector_type(4))) float f32x4;

#define GLOBAL_AS __attribute__((address_space(1)))
#define LDS_AS    __attribute__((address_space(3)))

__device__ __forceinline__ void gload16(const void* g, void* l) {
    __builtin_amdgcn_global_load_lds((const GLOBAL_AS unsigned int*)g,
                                     (LDS_AS unsigned int*)l, 16, 0, 0);
}

__device__ __forceinline__ u16 f2bf(float v) {
    unsigned int u = __float_as_uint(v);
    return (u16)((u + 0x7FFFu + ((u >> 16) & 1u)) >> 16);
}

// Tiled operand layout (both A and B):
//   byte = ((panel*NKT + kt) * 16384) + kk*8192 + sm*1024 + q*256 + fr*16 + j*2
// where row/col = panel*128 + sm*16 + fr, k = kt*64 + kk*32 + q*8 + j.
// Chunk index within a 16x32 subtile is (q*16 + fr) == the reading lane id,
// so every GEMM-side access (gload_lds dst AND ds_read_b128 src) is
// base + lane*16: linear, coalesced, bank-conflict-free.

// ---------------------------------------------------------------------------
// pack_A: rows = batch. slab 0 holds bf16(x); slabs 1..5 hold the one-hot
// interval indicators of rounded-tanh(x), classified in x-space with
// double-precision thresholds derived from the actual device grid.
// Each thread: 4 rows x 8 k-values -> 6 x 64B contiguous stores.
// ---------------------------------------------------------------------------
__global__ __launch_bounds__(256) void pack_A_kernel(
    const float* __restrict__ x, const float* __restrict__ grid,
    char* __restrict__ A)
{
    __shared__ double thr[5];
    if (threadIdx.x == 0) {
        #pragma unroll
        for (int k = 0; k < 4; ++k) {
            float gv = grid[k + 1];                 // -0.6, -0.2, 0.2, 0.6
            float below = nextafterf(gv, -2.0f);
            double mid = 0.5 * ((double)gv + (double)below);
            thr[k] = atanh(mid);
        }
        {
            float gv = grid[5];                     // 1.0
            float below = nextafterf(gv, 0.0f);
            double mid = 0.5 * ((double)gv + (double)below);
            thr[4] = atanh(mid);                    // ~9.01: tanh rounds to 1.0f
        }
    }
    __syncthreads();
    double t1 = thr[0], t2 = thr[1], t3 = thr[2], t4 = thr[3], t5 = thr[4];

    int gid = blockIdx.x * 256 + threadIdx.x;       // 0 .. 262143
    int rg  = gid >> 7;                             // 4-row group 0..2047
    int c   = gid & 127;                            // k-chunk of 8
    int b0  = rg << 2;
    int i0  = c << 3;

    int p   = b0 >> 7;
    int sm  = (b0 >> 4) & 7;
    int fr0 = b0 & 15;
    int ktb = c >> 3;                               // kt within a slab
    int kk  = (c >> 2) & 1;
    int q   = c & 3;

    u16 xb[4][8];
    int gi[4][8];
    #pragma unroll
    for (int r = 0; r < 4; ++r) {
        const float* xr = x + (size_t)(b0 + r) * IN_F + i0;
        float4 a = *(const float4*)xr;
        float4 b = *(const float4*)(xr + 4);
        float v[8] = {a.x, a.y, a.z, a.w, b.x, b.y, b.z, b.w};
        #pragma unroll
        for (int j = 0; j < 8; ++j) {
            xb[r][j] = f2bf(v[j]);
            double xd = (double)v[j];
            int g = (xd > t1) + (xd > t2) + (xd > t3) + (xd > t4);
            if (xd > t5) g = -1;                    // xn == 1.0f: no interval
            gi[r][j] = g;
        }
    }

    size_t base = (size_t)(p * NKT) * TILE_BYTES
                + (size_t)kk * 8192 + (size_t)sm * 1024 + (size_t)q * 256
                + (size_t)fr0 * 16;

    // slab 0: x values
    {
        size_t off = base + (size_t)ktb * TILE_BYTES;
        #pragma unroll
        for (int r = 0; r < 4; ++r) {
            u16x8 s;
            #pragma unroll
            for (int j = 0; j < 8; ++j) s[j] = xb[r][j];
            *(u16x8*)(A + off + r * 16) = s;
        }
    }
    // slabs 1..5: one-hot indicators
    #pragma unroll
    for (int g = 0; g < NSLAB; ++g) {
        size_t off = base + (size_t)((g + 1) * 16 + ktb) * TILE_BYTES;
        #pragma unroll
        for (int r = 0; r < 4; ++r) {
            u16x8 s;
            #pragma unroll
            for (int j = 0; j < 8; ++j)
                s[j] = (gi[r][j] == g) ? (u16)0x3F80 : (u16)0;
            *(u16x8*)(A + off + r * 16) = s;
        }
    }
}

// ---------------------------------------------------------------------------
// pack_B: rows = output features. slab 0 = bf16(base_weight);
// slabs 1..5 = bf16(spline_weight[.., g]). Same tiled image layout.
// ---------------------------------------------------------------------------
__global__ __launch_bounds__(256) void pack_B_kernel(
    const float* __restrict__ sw, const float* __restrict__ bw,
    char* __restrict__ Bt)
{
    int gid = blockIdx.x * 256 + threadIdx.x;       // 0 .. 32767
    int og  = gid >> 7;
    int c   = gid & 127;
    int o0  = og << 2;
    int i0  = c << 3;

    int pn  = o0 >> 7;
    int sn  = (o0 >> 4) & 7;
    int fc0 = o0 & 15;
    int ktb = c >> 3;
    int kk  = (c >> 2) & 1;
    int q   = c & 3;

    size_t base = (size_t)(pn * NKT) * TILE_BYTES
                + (size_t)kk * 8192 + (size_t)sn * 1024 + (size_t)q * 256
                + (size_t)fc0 * 16;

    #pragma unroll
    for (int r = 0; r < 4; ++r) {
        const float* bwr = bw + (size_t)(o0 + r) * IN_F + i0;
        float4 a = *(const float4*)bwr;
        float4 b = *(const float4*)(bwr + 4);
        float v[8] = {a.x, a.y, a.z, a.w, b.x, b.y, b.z, b.w};
        u16x8 s0;
        #pragma unroll
        for (int j = 0; j < 8; ++j) s0[j] = f2bf(v[j]);
        *(u16x8*)(Bt + base + (size_t)ktb * TILE_BYTES + r * 16) = s0;

        const float* swr = sw + ((size_t)(o0 + r) * IN_F + i0) * 8;
        float ch[8][5];
        #pragma unroll
        for (int j = 0; j < 8; ++j) {
            float4 lo = *(const float4*)(swr + j * 8);
            float4 hi = *(const float4*)(swr + j * 8 + 4);
            ch[j][0] = lo.x; ch[j][1] = lo.y; ch[j][2] = lo.z;
            ch[j][3] = lo.w; ch[j][4] = hi.x;
        }
        #pragma unroll
        for (int g = 0; g < NSLAB; ++g) {
            u16x8 s;
            #pragma unroll
            for (int j = 0; j < 8; ++j) s[j] = f2bf(ch[j][g]);
            *(u16x8*)(Bt + base + (size_t)((g + 1) * 16 + ktb) * TILE_BYTES + r * 16) = s;
        }
    }
}

// ---------------------------------------------------------------------------
// GEMM: C[8192,1024] f32 = A @ B^T over K=6144, 128x128 tile, BK=64,
// double-buffered LDS, 2-phase prefetch (stage t+1 issued before compute t,
// single __syncthreads()/K-step drains vmcnt after the MFMAs).
// 4 waves 2x2, per-wave 64x64 out = 4x4 frags of 16x16.
// ---------------------------------------------------------------------------
__device__ __forceinline__ void stage_tiles(const char* sa, const char* sb,
                                            char* la, char* lb, int tid) {
    #pragma unroll
    for (int j = 0; j < 4; ++j) {
        gload16(sa + tid * 16 + j * 4096, la + tid * 16 + j * 4096);
        gload16(sb + tid * 16 + j * 4096, lb + tid * 16 + j * 4096);
    }
}

__device__ __forceinline__ void compute_step(const char* ldsbuf, int lane,
                                             int wr, int wc, f32x4 acc[4][4]) {
    const u16* As = (const u16*)ldsbuf;
    const u16* Bs = As + 8192;                      // +16384 bytes
    bf16x8 af[2][4], bfv[2][4];
    #pragma unroll
    for (int kk = 0; kk < 2; ++kk) {
        #pragma unroll
        for (int m = 0; m < 4; ++m)
            af[kk][m] = *(const bf16x8*)(As + kk * 4096 + (wr * 4 + m) * 512 + lane * 8);
        #pragma unroll
        for (int n = 0; n < 4; ++n)
            bfv[kk][n] = *(const bf16x8*)(Bs + kk * 4096 + (wc * 4 + n) * 512 + lane * 8);
    }
    #pragma unroll
    for (int kk = 0; kk < 2; ++kk)
        #pragma unroll
        for (int m = 0; m < 4; ++m)
            #pragma unroll
            for (int n = 0; n < 4; ++n)
                acc[m][n] = __builtin_amdgcn_mfma_f32_16x16x32_bf16(
                    af[kk][m], bfv[kk][n], acc[m][n], 0, 0, 0);
}

__global__ __launch_bounds__(256, 2) void gemm_kernel(
    const char* __restrict__ At, const char* __restrict__ Bt,
    float* __restrict__ C)
{
    __shared__ __align__(16) char lds[65536];       // 2 bufs x (A 16KB | B 16KB)

    int tid = threadIdx.x;
    int bid = blockIdx.x;                           // 0..511

    // XCD swizzle: each XCD owns an 8x8 supertile of output tiles.
    int xcd  = bid & 7;
    int slot = bid >> 3;
    int tile = xcd * 64 + slot;
    int brow = tile >> 3;                           // 0..63
    int bcol = tile & 7;                            // 0..7

    int lane = tid & 63;
    int w    = tid >> 6;
    int wr   = w >> 1;
    int wc   = w & 1;

    const char* Ap = At + (size_t)brow * NKT * TILE_BYTES;
    const char* Bp = Bt + (size_t)bcol * NKT * TILE_BYTES;

    f32x4 acc[4][4];
    #pragma unroll
    for (int m = 0; m < 4; ++m)
        #pragma unroll
        for (int n = 0; n < 4; ++n)
            #pragma unroll
            for (int j = 0; j < 4; ++j)
                acc[m][n][j] = 0.0f;

    stage_tiles(Ap, Bp, lds, lds + 16384, tid);
    __syncthreads();

    for (int kt = 0; kt < NKT; kt += 2) {
        if (kt + 1 < NKT)
            stage_tiles(Ap + (size_t)(kt + 1) * TILE_BYTES,
                        Bp + (size_t)(kt + 1) * TILE_BYTES,
                        lds + 32768, lds + 49152, tid);
        compute_step(lds, lane, wr, wc, acc);
        __syncthreads();                            // drains vmcnt after MFMAs

        if (kt + 2 < NKT)
            stage_tiles(Ap + (size_t)(kt + 2) * TILE_BYTES,
                        Bp + (size_t)(kt + 2) * TILE_BYTES,
                        lds, lds + 16384, tid);
        compute_step(lds + 32768, lane, wr, wc, acc);
        __syncthreads();
    }

    // epilogue: C/D layout col = lane&15, row = (lane>>4)*4 + reg
    int crow0 = brow * 128 + wr * 64 + ((lane >> 4) << 2);
    int ccol0 = bcol * 128 + wc * 64 + (lane & 15);
    #pragma unroll
    for (int m = 0; m < 4; ++m)
        #pragma unroll
        for (int j = 0; j < 4; ++j) {
            size_t r = (size_t)(crow0 + m * 16 + j);
            float* cp = C + r * OUT_F + ccol0;
            #pragma unroll
            for (int n = 0; n < 4; ++n)
                cp[n * 16] = acc[m][n][j];
        }
}

// Fallback signal if workspace is too small: absmax will read ~12345.
__global__ void sentinel_kernel(float* out, int n) {
    int i = blockIdx.x * 256 + threadIdx.x;
    if (i < n) out[i] = (i == 0) ? 12345.0f : 0.0f;
}

extern "C" void kernel_launch(void* const* d_in, const int* in_sizes, int n_in,
                              void* d_out, int out_size, void* d_ws, size_t ws_size,
                              hipStream_t stream) {
    const float* x    = (const float*)d_in[0];
    const float* sw   = (const float*)d_in[1];
    const float* bw   = (const float*)d_in[2];
    const float* grid = (const float*)d_in[3];
    float* out = (float*)d_out;

    const size_t A_bytes = (size_t)64 * NKT * TILE_BYTES;   // 100,663,296
    const size_t B_bytes = (size_t)8  * NKT * TILE_BYTES;   //  12,582,912
    if (ws_size < A_bytes + B_bytes) {
        sentinel_kernel<<<(out_size + 255) / 256, 256, 0, stream>>>(out, out_size);
        return;
    }

    char* At = (char*)d_ws;
    char* Bt = (char*)d_ws + A_bytes;

    pack_A_kernel<<<1024, 256, 0, stream>>>(x, grid, At);
    pack_B_kernel<<<128, 256, 0, stream>>>(sw, bw, Bt);
    gemm_kernel<<<512, 256, 0, stream>>>(At, Bt, out);
}

// Round 3
// 151.322 us; speedup vs baseline: 1.1401x; 1.0186x over previous
//
#include <hip/hip_runtime.h>
#include <hip/hip_bf16.h>
#include <math.h>

#define B_DIM 8192
#define IN_F  1024
#define OUT_F 1024
#define NSLAB 5
#define K_DIM (IN_F * (1 + NSLAB))   // 6144
#define NKT   (K_DIM / 32)           // 192 K-tiles of 32
#define TILE_BYTES 8192              // one 128x32 bf16 tile image

typedef unsigned short u16;
typedef __attribute__((ext_vector_type(8))) short bf16x8;
typedef __attribute__((ext_vector_type(8))) unsigned short u16x8;
typedef __attribute__((ext_vector_type(4))) float f32x4;

#define GLOBAL_AS __attribute__((address_space(1)))
#define LDS_AS    __attribute__((address_space(3)))

__device__ __forceinline__ void gload16(const void* g, void* l) {
    __builtin_amdgcn_global_load_lds((const GLOBAL_AS unsigned int*)g,
                                     (LDS_AS unsigned int*)l, 16, 0, 0);
}

__device__ __forceinline__ u16 f2bf(float v) {
    unsigned int u = __float_as_uint(v);
    return (u16)((u + 0x7FFFu + ((u >> 16) & 1u)) >> 16);
}

// Tiled operand layout (both A and B), BK=32:
//   byte = ((panel*NKT + kt) * 8192) + sm*1024 + q*256 + fr*16 + j*2
// where row/col = panel*128 + sm*16 + fr, k = kt*32 + q*8 + j.
// Within a 16x32 subtile the chunk index (q*16+fr) equals the reading lane,
// so GEMM staging dst/src AND every ds_read_b128 are base + lane*16:
// linear, coalesced, bank-conflict-free.

// ---------------------------------------------------------------------------
// pack_A: rows = batch. slab 0 holds bf16(x); slabs 1..5 hold the one-hot
// interval indicators of rounded-tanh(x), classified in x-space with
// double-precision thresholds derived from the actual device grid.
// ---------------------------------------------------------------------------
__global__ __launch_bounds__(256) void pack_A_kernel(
    const float* __restrict__ x, const float* __restrict__ grid,
    char* __restrict__ A)
{
    __shared__ double thr[5];
    if (threadIdx.x == 0) {
        #pragma unroll
        for (int k = 0; k < 4; ++k) {
            float gv = grid[k + 1];                 // -0.6, -0.2, 0.2, 0.6
            float below = nextafterf(gv, -2.0f);
            double mid = 0.5 * ((double)gv + (double)below);
            thr[k] = atanh(mid);
        }
        {
            float gv = grid[5];                     // 1.0
            float below = nextafterf(gv, 0.0f);
            double mid = 0.5 * ((double)gv + (double)below);
            thr[4] = atanh(mid);                    // ~9.01: tanh rounds to 1.0f
        }
    }
    __syncthreads();
    double t1 = thr[0], t2 = thr[1], t3 = thr[2], t4 = thr[3], t5 = thr[4];

    int gid = blockIdx.x * 256 + threadIdx.x;       // 0 .. 262143
    int rg  = gid >> 7;                             // 4-row group 0..2047
    int c   = gid & 127;                            // k-chunk of 8
    int b0  = rg << 2;
    int i0  = c << 3;

    int p   = b0 >> 7;                              // panel 0..63
    int sm  = (b0 >> 4) & 7;
    int fr0 = b0 & 15;
    int ktb = c >> 2;                               // kt within a slab (0..31)
    int q   = c & 3;

    u16 xb[4][8];
    int gi[4][8];
    #pragma unroll
    for (int r = 0; r < 4; ++r) {
        const float* xr = x + (size_t)(b0 + r) * IN_F + i0;
        float4 a = *(const float4*)xr;
        float4 b = *(const float4*)(xr + 4);
        float v[8] = {a.x, a.y, a.z, a.w, b.x, b.y, b.z, b.w};
        #pragma unroll
        for (int j = 0; j < 8; ++j) {
            xb[r][j] = f2bf(v[j]);
            double xd = (double)v[j];
            int g = (xd > t1) + (xd > t2) + (xd > t3) + (xd > t4);
            if (xd > t5) g = -1;                    // xn == 1.0f: no interval
            gi[r][j] = g;
        }
    }

    size_t base = (size_t)(p * NKT) * TILE_BYTES
                + (size_t)sm * 1024 + (size_t)q * 256 + (size_t)fr0 * 16;

    // slab 0: x values  (tile index = ktb)
    {
        size_t off = base + (size_t)ktb * TILE_BYTES;
        #pragma unroll
        for (int r = 0; r < 4; ++r) {
            u16x8 s;
            #pragma unroll
            for (int j = 0; j < 8; ++j) s[j] = xb[r][j];
            *(u16x8*)(A + off + r * 16) = s;
        }
    }
    // slabs 1..5: one-hot indicators (tile index = (g+1)*32 + ktb)
    #pragma unroll
    for (int g = 0; g < NSLAB; ++g) {
        size_t off = base + (size_t)((g + 1) * 32 + ktb) * TILE_BYTES;
        #pragma unroll
        for (int r = 0; r < 4; ++r) {
            u16x8 s;
            #pragma unroll
            for (int j = 0; j < 8; ++j)
                s[j] = (gi[r][j] == g) ? (u16)0x3F80 : (u16)0;
            *(u16x8*)(A + off + r * 16) = s;
        }
    }
}

// ---------------------------------------------------------------------------
// pack_B: rows = output features. slab 0 = bf16(base_weight);
// slabs 1..5 = bf16(spline_weight[.., g]). Same tiled image layout.
// ---------------------------------------------------------------------------
__global__ __launch_bounds__(256) void pack_B_kernel(
    const float* __restrict__ sw, const float* __restrict__ bw,
    char* __restrict__ Bt)
{
    int gid = blockIdx.x * 256 + threadIdx.x;       // 0 .. 32767
    int og  = gid >> 7;
    int c   = gid & 127;
    int o0  = og << 2;
    int i0  = c << 3;

    int pn  = o0 >> 7;                              // panel 0..7
    int sn  = (o0 >> 4) & 7;
    int fc0 = o0 & 15;
    int ktb = c >> 2;
    int q   = c & 3;

    size_t base = (size_t)(pn * NKT) * TILE_BYTES
                + (size_t)sn * 1024 + (size_t)q * 256 + (size_t)fc0 * 16;

    #pragma unroll
    for (int r = 0; r < 4; ++r) {
        const float* bwr = bw + (size_t)(o0 + r) * IN_F + i0;
        float4 a = *(const float4*)bwr;
        float4 b = *(const float4*)(bwr + 4);
        float v[8] = {a.x, a.y, a.z, a.w, b.x, b.y, b.z, b.w};
        u16x8 s0;
        #pragma unroll
        for (int j = 0; j < 8; ++j) s0[j] = f2bf(v[j]);
        *(u16x8*)(Bt + base + (size_t)ktb * TILE_BYTES + r * 16) = s0;

        const float* swr = sw + ((size_t)(o0 + r) * IN_F + i0) * 8;
        float ch[8][5];
        #pragma unroll
        for (int j = 0; j < 8; ++j) {
            float4 lo = *(const float4*)(swr + j * 8);
            float4 hi = *(const float4*)(swr + j * 8 + 4);
            ch[j][0] = lo.x; ch[j][1] = lo.y; ch[j][2] = lo.z;
            ch[j][3] = lo.w; ch[j][4] = hi.x;
        }
        #pragma unroll
        for (int g = 0; g < NSLAB; ++g) {
            u16x8 s;
            #pragma unroll
            for (int j = 0; j < 8; ++j) s[j] = f2bf(ch[j][g]);
            *(u16x8*)(Bt + base + (size_t)((g + 1) * 32 + ktb) * TILE_BYTES + r * 16) = s;
        }
    }
}

// ---------------------------------------------------------------------------
// GEMM: C[8192,1024] f32 = A @ B^T over K=6144. 128x128 tile, BK=32,
// 4-buffer LDS ring (64 KB), depth-3 prefetch with counted vmcnt (T3+T4),
// single raw s_barrier per K-step, setprio around the MFMA cluster (T5).
// 4 waves 2x2, per-wave 64x64 out = 4x4 frags of 16x16.
// ---------------------------------------------------------------------------
__device__ __forceinline__ void stage_tile(const char* Ap, const char* Bp,
                                           int kt, char* buf, int tid) {
    const char* sa = Ap + (size_t)kt * TILE_BYTES;
    const char* sb = Bp + (size_t)kt * TILE_BYTES;
    gload16(sa + tid * 16,        buf + tid * 16);
    gload16(sa + tid * 16 + 4096, buf + tid * 16 + 4096);
    gload16(sb + tid * 16,        buf + 8192 + tid * 16);
    gload16(sb + tid * 16 + 4096, buf + 8192 + tid * 16 + 4096);
}

__device__ __forceinline__ void compute_tile(const char* buf, int lane,
                                             int wr, int wc, f32x4 acc[4][4]) {
    const u16* As = (const u16*)buf;
    const u16* Bs = As + 4096;                      // +8192 bytes
    bf16x8 af[4], bfv[4];
    #pragma unroll
    for (int m = 0; m < 4; ++m)
        af[m] = *(const bf16x8*)(As + (wr * 4 + m) * 512 + lane * 8);
    #pragma unroll
    for (int n = 0; n < 4; ++n)
        bfv[n] = *(const bf16x8*)(Bs + (wc * 4 + n) * 512 + lane * 8);

    __builtin_amdgcn_s_setprio(1);
    #pragma unroll
    for (int m = 0; m < 4; ++m)
        #pragma unroll
        for (int n = 0; n < 4; ++n)
            acc[m][n] = __builtin_amdgcn_mfma_f32_16x16x32_bf16(
                af[m], bfv[n], acc[m][n], 0, 0, 0);
    __builtin_amdgcn_s_setprio(0);
}

__global__ __launch_bounds__(256, 2) void gemm_kernel(
    const char* __restrict__ At, const char* __restrict__ Bt,
    float* __restrict__ C)
{
    __shared__ __align__(16) char lds[4 * 16384];   // 4-buffer ring, 64 KB

    int tid = threadIdx.x;
    int bid = blockIdx.x;                           // 0..511

    // XCD swizzle: each XCD owns an 8x8 supertile of output tiles.
    int xcd  = bid & 7;
    int slot = bid >> 3;
    int tile = xcd * 64 + slot;
    int brow = tile >> 3;                           // 0..63
    int bcol = tile & 7;                            // 0..7

    int lane = tid & 63;
    int w    = tid >> 6;
    int wr   = w >> 1;
    int wc   = w & 1;

    const char* Ap = At + (size_t)brow * NKT * TILE_BYTES;
    const char* Bp = Bt + (size_t)bcol * NKT * TILE_BYTES;

    f32x4 acc[4][4];
    #pragma unroll
    for (int m = 0; m < 4; ++m)
        #pragma unroll
        for (int n = 0; n < 4; ++n)
            #pragma unroll
            for (int j = 0; j < 4; ++j)
                acc[m][n][j] = 0.0f;

    // prologue: fill 3 ring slots (12 loads in flight)
    stage_tile(Ap, Bp, 0, lds,          tid);
    stage_tile(Ap, Bp, 1, lds + 16384,  tid);
    stage_tile(Ap, Bp, 2, lds + 32768,  tid);

    for (int t = 0; t < NKT; ++t) {
        // wait for stage(t): leave later stages' loads in flight (counted vmcnt)
        if (t < NKT - 2)       asm volatile("s_waitcnt vmcnt(8)" ::: "memory");
        else if (t == NKT - 2) asm volatile("s_waitcnt vmcnt(4)" ::: "memory");
        else                   asm volatile("s_waitcnt vmcnt(0)" ::: "memory");
        __builtin_amdgcn_s_barrier();               // publishes stage(t); fences
        asm volatile("" ::: "memory");              // compute(t-1) vs stage(t+3)

        if (t + 3 < NKT)
            stage_tile(Ap, Bp, t + 3, lds + ((t + 3) & 3) * 16384, tid);

        compute_tile(lds + (t & 3) * 16384, lane, wr, wc, acc);
    }

    // epilogue: C/D layout col = lane&15, row = (lane>>4)*4 + reg
    int crow0 = brow * 128 + wr * 64 + ((lane >> 4) << 2);
    int ccol0 = bcol * 128 + wc * 64 + (lane & 15);
    #pragma unroll
    for (int m = 0; m < 4; ++m)
        #pragma unroll
        for (int j = 0; j < 4; ++j) {
            size_t r = (size_t)(crow0 + m * 16 + j);
            float* cp = C + r * OUT_F + ccol0;
            #pragma unroll
            for (int n = 0; n < 4; ++n)
                cp[n * 16] = acc[m][n][j];
        }
}

// Fallback signal if workspace is too small: absmax will read ~12345.
__global__ void sentinel_kernel(float* out, int n) {
    int i = blockIdx.x * 256 + threadIdx.x;
    if (i < n) out[i] = (i == 0) ? 12345.0f : 0.0f;
}

extern "C" void kernel_launch(void* const* d_in, const int* in_sizes, int n_in,
                              void* d_out, int out_size, void* d_ws, size_t ws_size,
                              hipStream_t stream) {
    const float* x    = (const float*)d_in[0];
    const float* sw   = (const float*)d_in[1];
    const float* bw   = (const float*)d_in[2];
    const float* grid = (const float*)d_in[3];
    float* out = (float*)d_out;

    const size_t A_bytes = (size_t)64 * NKT * TILE_BYTES;   // 100,663,296
    const size_t B_bytes = (size_t)8  * NKT * TILE_BYTES;   //  12,582,912
    if (ws_size < A_bytes + B_bytes) {
        sentinel_kernel<<<(out_size + 255) / 256, 256, 0, stream>>>(out, out_size);
        return;
    }

    char* At = (char*)d_ws;
    char* Bt = (char*)d_ws + A_bytes;

    pack_A_kernel<<<1024, 256, 0, stream>>>(x, grid, At);
    pack_B_kernel<<<128, 256, 0, stream>>>(sw, bw, Bt);
    gemm_kernel<<<512, 256, 0, stream>>>(At, Bt, out);
}

// Round 4
// 141.158 us; speedup vs baseline: 1.2222x; 1.0720x over previous
//
#include <hip/hip_runtime.h>
#include <hip/hip_bf16.h>
#include <math.h>

#define B_DIM 8192
#define IN_F  1024
#define OUT_F 1024
#define NSLAB 5
#define K_DIM (IN_F * (1 + NSLAB))   // 6144
#define NKT   (K_DIM / 32)           // 192 K-tiles of 32
#define TILE_BYTES 8192              // one 128x32 bf16 tile image

typedef unsigned short u16;
typedef __attribute__((ext_vector_type(8))) short bf16x8;
typedef __attribute__((ext_vector_type(8))) unsigned short u16x8;
typedef __attribute__((ext_vector_type(4))) float f32x4;

#define GLOBAL_AS __attribute__((address_space(1)))
#define LDS_AS    __attribute__((address_space(3)))

__device__ __forceinline__ void gload16(const void* g, void* l) {
    __builtin_amdgcn_global_load_lds((const GLOBAL_AS unsigned int*)g,
                                     (LDS_AS unsigned int*)l, 16, 0, 0);
}

__device__ __forceinline__ u16 f2bf(float v) {
    unsigned int u = __float_as_uint(v);
    return (u16)((u + 0x7FFFu + ((u >> 16) & 1u)) >> 16);
}

// Tiled operand layout (both A and B), BK=32:
//   byte = ((panel*NKT + kt) * 8192) + sm*1024 + lane*16
// where lane -> (fr = lane&15 row-in-subtile, q = lane>>4 k-chunk),
// row/col = panel*128 + sm*16 + fr, k = kt*32 + q*8 + j.
// Every consumer access (gload_lds dst, ds_read_b128, global B-frag load)
// is base + lane*16: linear, coalesced, bank-conflict-free.

// ---------------------------------------------------------------------------
// pack_A: rows = batch. slab 0 = bf16(x); slabs 1..5 = one-hot interval
// indicators of rounded-tanh(x), classified in x-space with double-precision
// thresholds from the actual device grid. One wave per (p,sm,ktb) subtile:
// each store is a full contiguous 1KB wave-chunk (lane*16).
// ---------------------------------------------------------------------------
__global__ __launch_bounds__(256) void pack_A_kernel(
    const float* __restrict__ x, const float* __restrict__ grid,
    char* __restrict__ A)
{
    __shared__ double thr[5];
    if (threadIdx.x == 0) {
        #pragma unroll
        for (int k = 0; k < 4; ++k) {
            float gv = grid[k + 1];                 // -0.6, -0.2, 0.2, 0.6
            float below = nextafterf(gv, -2.0f);
            double mid = 0.5 * ((double)gv + (double)below);
            thr[k] = atanh(mid);
        }
        {
            float gv = grid[5];                     // 1.0
            float below = nextafterf(gv, 0.0f);
            double mid = 0.5 * ((double)gv + (double)below);
            thr[4] = atanh(mid);                    // ~9.01: tanh rounds to 1.0f
        }
    }
    __syncthreads();
    double t1 = thr[0], t2 = thr[1], t3 = thr[2], t4 = thr[3], t5 = thr[4];

    int gid  = blockIdx.x * 256 + threadIdx.x;      // 1,048,576 threads
    int lane = gid & 63;
    int wav  = gid >> 6;                            // 16384 waves
    int ktb  = wav & 31;
    int sm   = (wav >> 5) & 7;
    int p    = wav >> 8;                            // 0..63
    int fr   = lane & 15;
    int q    = lane >> 4;

    int b  = p * 128 + sm * 16 + fr;
    int i0 = ktb * 32 + q * 8;

    const float* xr = x + (size_t)b * IN_F + i0;
    float4 a0 = *(const float4*)xr;
    float4 a1 = *(const float4*)(xr + 4);
    float v[8] = {a0.x, a0.y, a0.z, a0.w, a1.x, a1.y, a1.z, a1.w};

    u16 xb[8];
    int gi[8];
    #pragma unroll
    for (int j = 0; j < 8; ++j) {
        xb[j] = f2bf(v[j]);
        double xd = (double)v[j];
        int g = (xd > t1) + (xd > t2) + (xd > t3) + (xd > t4);
        if (xd > t5) g = -1;                        // xn == 1.0f: no interval
        gi[j] = g;
    }

    size_t tb = ((size_t)(p * NKT + ktb)) * TILE_BYTES
              + (size_t)sm * 1024 + (size_t)lane * 16;

    u16x8 s;
    #pragma unroll
    for (int j = 0; j < 8; ++j) s[j] = xb[j];
    *(u16x8*)(A + tb) = s;

    #pragma unroll
    for (int g = 0; g < NSLAB; ++g) {
        u16x8 oh;
        #pragma unroll
        for (int j = 0; j < 8; ++j)
            oh[j] = (gi[j] == g) ? (u16)0x3F80 : (u16)0;
        *(u16x8*)(A + tb + (size_t)(g + 1) * 32 * TILE_BYTES) = oh;
    }
}

// ---------------------------------------------------------------------------
// pack_B: rows = output features. slab 0 = bf16(base_weight);
// slabs 1..5 = bf16(spline_weight[..,g]). Same wave-chunk store pattern.
// ---------------------------------------------------------------------------
__global__ __launch_bounds__(256) void pack_B_kernel(
    const float* __restrict__ sw, const float* __restrict__ bw,
    char* __restrict__ Bt)
{
    int gid  = blockIdx.x * 256 + threadIdx.x;      // 131072 threads
    int lane = gid & 63;
    int wav  = gid >> 6;                            // 2048 waves
    int ktb  = wav & 31;
    int sn   = (wav >> 5) & 7;
    int p    = wav >> 8;                            // 0..7
    int fc   = lane & 15;
    int q    = lane >> 4;

    int o  = p * 128 + sn * 16 + fc;
    int i0 = ktb * 32 + q * 8;

    size_t tb = ((size_t)(p * NKT + ktb)) * TILE_BYTES
              + (size_t)sn * 1024 + (size_t)lane * 16;

    const float* bwr = bw + (size_t)o * IN_F + i0;
    float4 b0 = *(const float4*)bwr;
    float4 b1 = *(const float4*)(bwr + 4);
    float v[8] = {b0.x, b0.y, b0.z, b0.w, b1.x, b1.y, b1.z, b1.w};
    u16x8 s0;
    #pragma unroll
    for (int j = 0; j < 8; ++j) s0[j] = f2bf(v[j]);
    *(u16x8*)(Bt + tb) = s0;

    float ch[8][5];
    #pragma unroll
    for (int j = 0; j < 8; ++j) {
        const float* swr = sw + ((size_t)o * IN_F + i0 + j) * 8;
        float4 lo = *(const float4*)swr;
        float4 hi = *(const float4*)(swr + 4);
        ch[j][0] = lo.x; ch[j][1] = lo.y; ch[j][2] = lo.z;
        ch[j][3] = lo.w; ch[j][4] = hi.x;
    }
    #pragma unroll
    for (int g = 0; g < NSLAB; ++g) {
        u16x8 s;
        #pragma unroll
        for (int j = 0; j < 8; ++j) s[j] = f2bf(ch[j][g]);
        *(u16x8*)(Bt + tb + (size_t)(g + 1) * 32 * TILE_BYTES) = s;
    }
}

// ---------------------------------------------------------------------------
// GEMM: C[8192,1024] f32 = A @ B^T over K=6144. 128x128 tile, BK=32.
// A: 4-buffer LDS ring (32 KB), depth-3 prefetch via global_load_lds.
// B: direct global->register fragments (L2-served), depth-2 prefetch,
//    4 register buffers, loop unrolled x4 so all indices are static.
// Counted vmcnt(6) keeps A(t+2)+B(t+1) in flight across the barrier.
// 4 waves 2x2, per-wave 64x64 out = 4x4 frags of 16x16.
// ---------------------------------------------------------------------------
__device__ __forceinline__ void stage_A(const char* Ap, int kt, char* dst, int tid) {
    const char* sa = Ap + (size_t)kt * TILE_BYTES;
    gload16(sa + tid * 16,        dst + tid * 16);
    gload16(sa + tid * 16 + 4096, dst + tid * 16 + 4096);
}

__device__ __forceinline__ void load_bfrag(const char* Bw, int kt, bf16x8* dst) {
    const char* sb = Bw + (size_t)kt * TILE_BYTES;
    dst[0] = *(const bf16x8*)(sb);
    dst[1] = *(const bf16x8*)(sb + 1024);
    dst[2] = *(const bf16x8*)(sb + 2048);
    dst[3] = *(const bf16x8*)(sb + 3072);
}

template <int I, int WN>
__device__ __forceinline__ void gemm_step(int t, const char* Ap, const char* Bw,
                                          char* lds, bf16x8 bb[4][4],
                                          f32x4 acc[4][4],
                                          int tid, int lane, int wr) {
    if constexpr (WN == 6) asm volatile("s_waitcnt vmcnt(6)" ::: "memory");
    else                   asm volatile("s_waitcnt vmcnt(0)" ::: "memory");
    __builtin_amdgcn_s_barrier();                   // publishes A(t)
    asm volatile("" ::: "memory");

    if (t + 3 < NKT)
        stage_A(Ap, t + 3, lds + ((I + 3) & 3) * TILE_BYTES, tid);
    if (t + 2 < NKT)
        load_bfrag(Bw, t + 2, bb[(I + 2) & 3]);

    const char* buf = lds + (I & 3) * TILE_BYTES;
    bf16x8 af[4];
    #pragma unroll
    for (int m = 0; m < 4; ++m)
        af[m] = *(const bf16x8*)(buf + (wr * 4 + m) * 1024 + lane * 16);

    __builtin_amdgcn_s_setprio(1);
    #pragma unroll
    for (int m = 0; m < 4; ++m)
        #pragma unroll
        for (int n = 0; n < 4; ++n)
            acc[m][n] = __builtin_amdgcn_mfma_f32_16x16x32_bf16(
                af[m], bb[I & 3][n], acc[m][n], 0, 0, 0);
    __builtin_amdgcn_s_setprio(0);
}

__global__ __launch_bounds__(256, 2) void gemm_kernel(
    const char* __restrict__ At, const char* __restrict__ Bt,
    float* __restrict__ C)
{
    __shared__ __align__(16) char lds[4 * TILE_BYTES];   // A-only ring, 32 KB

    int tid = threadIdx.x;
    int bid = blockIdx.x;                           // 0..511

    // XCD swizzle: same-brow blocks land on one XCD (A-panel L2 sharing).
    int xcd  = bid & 7;
    int slot = bid >> 3;
    int tile = xcd * 64 + slot;
    int brow = tile >> 3;                           // 0..63
    int bcol = tile & 7;                            // 0..7

    int lane = tid & 63;
    int w    = tid >> 6;
    int wr   = w >> 1;
    int wc   = w & 1;

    const char* Ap = At + (size_t)brow * NKT * TILE_BYTES;
    const char* Bw = Bt + (size_t)bcol * NKT * TILE_BYTES
                   + (size_t)(wc * 4) * 1024 + (size_t)lane * 16;

    f32x4 acc[4][4];
    #pragma unroll
    for (int m = 0; m < 4; ++m)
        #pragma unroll
        for (int n = 0; n < 4; ++n)
            #pragma unroll
            for (int j = 0; j < 4; ++j)
                acc[m][n][j] = 0.0f;

    bf16x8 bb[4][4];

    // prologue: A depth-3, B depth-2. Newest 6 VMEM ops = B(1)[4] + A(2)[2].
    stage_A(Ap, 0, lds,                  tid);
    stage_A(Ap, 1, lds + TILE_BYTES,     tid);
    load_bfrag(Bw, 0, bb[0]);
    load_bfrag(Bw, 1, bb[1]);
    stage_A(Ap, 2, lds + 2 * TILE_BYTES, tid);

    #pragma unroll 1
    for (int t = 0; t < NKT - 8; t += 4) {
        gemm_step<0, 6>(t + 0, Ap, Bw, lds, bb, acc, tid, lane, wr);
        gemm_step<1, 6>(t + 1, Ap, Bw, lds, bb, acc, tid, lane, wr);
        gemm_step<2, 6>(t + 2, Ap, Bw, lds, bb, acc, tid, lane, wr);
        gemm_step<3, 6>(t + 3, Ap, Bw, lds, bb, acc, tid, lane, wr);
    }
    gemm_step<0, 6>(NKT - 8, Ap, Bw, lds, bb, acc, tid, lane, wr);
    gemm_step<1, 6>(NKT - 7, Ap, Bw, lds, bb, acc, tid, lane, wr);
    gemm_step<2, 6>(NKT - 6, Ap, Bw, lds, bb, acc, tid, lane, wr);
    gemm_step<3, 6>(NKT - 5, Ap, Bw, lds, bb, acc, tid, lane, wr);
    gemm_step<0, 0>(NKT - 4, Ap, Bw, lds, bb, acc, tid, lane, wr);
    gemm_step<1, 0>(NKT - 3, Ap, Bw, lds, bb, acc, tid, lane, wr);
    gemm_step<2, 0>(NKT - 2, Ap, Bw, lds, bb, acc, tid, lane, wr);
    gemm_step<3, 0>(NKT - 1, Ap, Bw, lds, bb, acc, tid, lane, wr);

    // epilogue: C/D layout col = lane&15, row = (lane>>4)*4 + reg
    int crow0 = brow * 128 + wr * 64 + ((lane >> 4) << 2);
    int ccol0 = bcol * 128 + wc * 64 + (lane & 15);
    #pragma unroll
    for (int m = 0; m < 4; ++m)
        #pragma unroll
        for (int j = 0; j < 4; ++j) {
            size_t r = (size_t)(crow0 + m * 16 + j);
            float* cp = C + r * OUT_F + ccol0;
            #pragma unroll
            for (int n = 0; n < 4; ++n)
                cp[n * 16] = acc[m][n][j];
        }
}

// Fallback signal if workspace is too small: absmax will read ~12345.
__global__ void sentinel_kernel(float* out, int n) {
    int i = blockIdx.x * 256 + threadIdx.x;
    if (i < n) out[i] = (i == 0) ? 12345.0f : 0.0f;
}

extern "C" void kernel_launch(void* const* d_in, const int* in_sizes, int n_in,
                              void* d_out, int out_size, void* d_ws, size_t ws_size,
                              hipStream_t stream) {
    const float* x    = (const float*)d_in[0];
    const float* sw   = (const float*)d_in[1];
    const float* bw   = (const float*)d_in[2];
    const float* grid = (const float*)d_in[3];
    float* out = (float*)d_out;

    const size_t A_bytes = (size_t)64 * NKT * TILE_BYTES;   // 100,663,296
    const size_t B_bytes = (size_t)8  * NKT * TILE_BYTES;   //  12,582,912
    if (ws_size < A_bytes + B_bytes) {
        sentinel_kernel<<<(out_size + 255) / 256, 256, 0, stream>>>(out, out_size);
        return;
    }

    char* At = (char*)d_ws;
    char* Bt = (char*)d_ws + A_bytes;

    pack_A_kernel<<<4096, 256, 0, stream>>>(x, grid, At);
    pack_B_kernel<<<512, 256, 0, stream>>>(sw, bw, Bt);
    gemm_kernel<<<512, 256, 0, stream>>>(At, Bt, out);
}

// Round 5
// 125.402 us; speedup vs baseline: 1.3758x; 1.1256x over previous
//
#include <hip/hip_runtime.h>
#include <hip/hip_bf16.h>
#include <math.h>

#define B_DIM 8192
#define IN_F  1024
#define OUT_F 1024
#define NKTB  160                    // 5 slabs x 32 k-tiles of 32 (K=5120)

typedef unsigned short u16;
typedef __attribute__((ext_vector_type(8))) short bf16x8;
typedef __attribute__((ext_vector_type(8))) unsigned short u16x8;
typedef __attribute__((ext_vector_type(4))) float f32x4;

__device__ __forceinline__ u16 f2bf(float v) {
    unsigned int u = __float_as_uint(v);
    return (u16)((u + 0x7FFFu + ((u >> 16) & 1u)) >> 16);
}

// ---------------------------------------------------------------------------
// B image: slab 0 = bf16(base_weight); slabs 1..4 = bf16(sw_s - sw_{s-1}).
// Tile (s,ktb) at byte ((p*NKTB + s*32 + ktb)*8192) + sn*1024 + lane*16,
// lane -> (fc=lane&15 col, q=lane>>4 k-octet): every GEMM B-frag load is
// one contiguous 16B chunk per lane.
// ---------------------------------------------------------------------------
__global__ __launch_bounds__(256) void pack_B_kernel(
    const float* __restrict__ sw, const float* __restrict__ bw,
    char* __restrict__ Bt)
{
    int gid  = blockIdx.x * 256 + threadIdx.x;      // 131072 threads
    int lane = gid & 63;
    int wav  = gid >> 6;                            // 2048 waves
    int ktb  = wav & 31;
    int sn   = (wav >> 5) & 7;
    int p    = wav >> 8;                            // 0..7
    int fc   = lane & 15;
    int q    = lane >> 4;

    int o  = p * 128 + sn * 16 + fc;
    int i0 = ktb * 32 + q * 8;

    size_t tb = ((size_t)(p * NKTB + ktb)) * 8192
              + (size_t)sn * 1024 + (size_t)lane * 16;

    const float* bwr = bw + (size_t)o * IN_F + i0;
    float4 b0 = *(const float4*)bwr;
    float4 b1 = *(const float4*)(bwr + 4);
    float v[8] = {b0.x, b0.y, b0.z, b0.w, b1.x, b1.y, b1.z, b1.w};
    u16x8 s0;
    #pragma unroll
    for (int j = 0; j < 8; ++j) s0[j] = f2bf(v[j]);
    *(u16x8*)(Bt + tb) = s0;                        // slab 0

    float c[8][5];
    #pragma unroll
    for (int j = 0; j < 8; ++j) {
        const float* swr = sw + ((size_t)o * IN_F + i0 + j) * 8;
        float4 lo = *(const float4*)swr;
        float4 hi = *(const float4*)(swr + 4);
        c[j][0] = lo.x; c[j][1] = lo.y; c[j][2] = lo.z;
        c[j][3] = lo.w; c[j][4] = hi.x;
    }
    #pragma unroll
    for (int s = 1; s < 5; ++s) {
        u16x8 d;
        #pragma unroll
        for (int j = 0; j < 8; ++j) d[j] = f2bf(c[j][s] - c[j][s - 1]);
        *(u16x8*)(Bt + tb + (size_t)(s * 32) * 8192) = d;
    }
}

// ---------------------------------------------------------------------------
// bias[o] = sum_i sw[o,i,0]  (T_0 == 1 for all in-range x), f32-exact.
// Also writes the 4 x-space step thresholds: smallest f32 T with
// (x >= T) <=> ((double)x > atanh(midpoint(grid[s], prevfloat(grid[s])))),
// replicating a correctly-rounded tanh's interval comparisons.
// ---------------------------------------------------------------------------
__global__ __launch_bounds__(256) void bias_thresh_kernel(
    const float* __restrict__ sw, const float* __restrict__ grid,
    float* __restrict__ biasT)
{
    int o    = blockIdx.x * 4 + (threadIdx.x >> 6);
    int lane = threadIdx.x & 63;
    float s = 0.f;
    #pragma unroll
    for (int j = 0; j < 16; ++j)
        s += sw[((size_t)o * IN_F + j * 64 + lane) * 8];
    #pragma unroll
    for (int off = 32; off; off >>= 1)
        s += __shfl_down(s, off);
    if (lane == 0) biasT[o] = s;

    if (blockIdx.x == 0 && threadIdx.x == 0) {
        #pragma unroll
        for (int k = 0; k < 4; ++k) {
            float gv = grid[k + 1];                 // -0.6, -0.2, 0.2, 0.6
            float below = nextafterf(gv, -2.0f);
            double mid = 0.5 * ((double)gv + (double)below);
            double t = atanh(mid);
            float Tf = (float)t;
            if (!((double)Tf > t)) Tf = nextafterf(Tf, 3.0f);
            biasT[1024 + k] = Tf;
        }
    }
}

// ---------------------------------------------------------------------------
// Fused GEMM: C = [bf16(x) | 1[x>=T_s]] @ B^T + bias. No LDS, no barriers.
// A-fragments built in registers from x; B streamed global->reg (dbuf).
// 512 blocks x 4 waves; wave = 64x64 out = 4x4 frags; 160 K-steps of 32.
// ---------------------------------------------------------------------------
__device__ __forceinline__ void load_x(const float* xb, int g, float xg[4][8]) {
    #pragma unroll
    for (int m = 0; m < 4; ++m) {
        const float* p = xb + (size_t)m * 16 * IN_F + g * 32;
        float4 a = *(const float4*)p;
        float4 b = *(const float4*)(p + 4);
        xg[m][0] = a.x; xg[m][1] = a.y; xg[m][2] = a.z; xg[m][3] = a.w;
        xg[m][4] = b.x; xg[m][5] = b.y; xg[m][6] = b.z; xg[m][7] = b.w;
    }
}

__device__ __forceinline__ void load_b(const char* Bw, int tileIdx, bf16x8 bb[4]) {
    const char* p = Bw + (size_t)tileIdx * 8192;
    bb[0] = *(const bf16x8*)(p);
    bb[1] = *(const bf16x8*)(p + 1024);
    bb[2] = *(const bf16x8*)(p + 2048);
    bb[3] = *(const bf16x8*)(p + 3072);
}

template <bool CVT>
__device__ __forceinline__ void do_step(const float xg[4][8], float T,
                                        const bf16x8 bb[4], f32x4 acc[4][4]) {
    bf16x8 af[4];
    #pragma unroll
    for (int m = 0; m < 4; ++m) {
        union { unsigned int u[4]; bf16x8 v; } t;
        #pragma unroll
        for (int p = 0; p < 4; ++p) {
            if constexpr (CVT) {
                unsigned int lo = f2bf(xg[m][2 * p]);
                unsigned int hi = f2bf(xg[m][2 * p + 1]);
                t.u[p] = lo | (hi << 16);
            } else {
                t.u[p] = (xg[m][2 * p]     >= T ? 0x00003F80u : 0u)
                       | (xg[m][2 * p + 1] >= T ? 0x3F800000u : 0u);
            }
        }
        af[m] = t.v;
    }
    __builtin_amdgcn_s_setprio(1);
    #pragma unroll
    for (int m = 0; m < 4; ++m)
        #pragma unroll
        for (int n = 0; n < 4; ++n)
            acc[m][n] = __builtin_amdgcn_mfma_f32_16x16x32_bf16(
                af[m], bb[n], acc[m][n], 0, 0, 0);
    __builtin_amdgcn_s_setprio(0);
}

__global__ __launch_bounds__(256, 2) void gemm_kernel(
    const float* __restrict__ x, const char* __restrict__ Bt,
    const float* __restrict__ biasT, float* __restrict__ C)
{
    int tid = threadIdx.x;
    int bid = blockIdx.x;                           // 0..511

    // XCD swizzle: each XCD owns an 8x8 supertile (A-panels stay per-XCD).
    int xcd  = bid & 7;
    int slot = bid >> 3;
    int tile = xcd * 64 + slot;
    int brow = tile >> 3;                           // 0..63
    int bcol = tile & 7;                            // 0..7

    int lane = tid & 63;
    int w    = tid >> 6;
    int wr   = w >> 1;
    int wc   = w & 1;
    int fr   = lane & 15;
    int q    = lane >> 4;

    float T1 = biasT[1024], T2 = biasT[1025], T3 = biasT[1026], T4 = biasT[1027];

    const float* xb = x + (size_t)(brow * 128 + wr * 64 + fr) * IN_F + q * 8;
    const char*  Bw = Bt + (size_t)bcol * NKTB * 8192
                    + (size_t)(wc * 4) * 1024 + (size_t)lane * 16;

    f32x4 acc[4][4];
    #pragma unroll
    for (int m = 0; m < 4; ++m)
        #pragma unroll
        for (int n = 0; n < 4; ++n)
            #pragma unroll
            for (int j = 0; j < 4; ++j)
                acc[m][n][j] = 0.0f;

    float xc[4][8], xn[4][8];
    bf16x8 bbA[4], bbB[4];
    load_x(xb, 0, xc);
    load_b(Bw, 0, bbA);                             // (s=0, g=0)

    #pragma unroll 1
    for (int it = 0; it < 16; ++it) {
        int g0 = 2 * it, g1 = 2 * it + 1;
        load_b(Bw,  32 + g0, bbB);                         do_step<true >(xc, 0.f, bbA, acc);
        load_b(Bw,  64 + g0, bbA); load_x(xb, g1, xn);     do_step<false>(xc, T1,  bbB, acc);
        load_b(Bw,  96 + g0, bbB);                         do_step<false>(xc, T2,  bbA, acc);
        load_b(Bw, 128 + g0, bbA);                         do_step<false>(xc, T3,  bbB, acc);
        load_b(Bw,        g1, bbB);                        do_step<false>(xc, T4,  bbA, acc);
        load_b(Bw,  32 + g1, bbA);                         do_step<true >(xn, 0.f, bbB, acc);
        load_b(Bw,  64 + g1, bbB);
        if (it < 15) load_x(xb, g0 + 2, xc);
                                                           do_step<false>(xn, T1,  bbA, acc);
        load_b(Bw,  96 + g1, bbA);                         do_step<false>(xn, T2,  bbB, acc);
        load_b(Bw, 128 + g1, bbB);                         do_step<false>(xn, T3,  bbA, acc);
        if (it < 15) load_b(Bw, g0 + 2, bbA);
                                                           do_step<false>(xn, T4,  bbB, acc);
    }

    // epilogue: C/D layout col = lane&15, row = (lane>>4)*4 + reg; add bias.
    int crow0 = brow * 128 + wr * 64 + (q << 2);
    int ccol0 = bcol * 128 + wc * 64 + fr;
    float bv[4];
    #pragma unroll
    for (int n = 0; n < 4; ++n) bv[n] = biasT[ccol0 + n * 16];
    #pragma unroll
    for (int m = 0; m < 4; ++m)
        #pragma unroll
        for (int j = 0; j < 4; ++j) {
            size_t r = (size_t)(crow0 + m * 16 + j);
            float* cp = C + r * OUT_F + ccol0;
            #pragma unroll
            for (int n = 0; n < 4; ++n)
                cp[n * 16] = acc[m][n][j] + bv[n];
        }
}

// Fallback signal if workspace is too small: absmax will read ~12345.
__global__ void sentinel_kernel(float* out, int n) {
    int i = blockIdx.x * 256 + threadIdx.x;
    if (i < n) out[i] = (i == 0) ? 12345.0f : 0.0f;
}

extern "C" void kernel_launch(void* const* d_in, const int* in_sizes, int n_in,
                              void* d_out, int out_size, void* d_ws, size_t ws_size,
                              hipStream_t stream) {
    const float* x    = (const float*)d_in[0];
    const float* sw   = (const float*)d_in[1];
    const float* bw   = (const float*)d_in[2];
    const float* grid = (const float*)d_in[3];
    float* out = (float*)d_out;

    const size_t B_bytes = (size_t)8 * NKTB * 8192;     // 10,485,760
    const size_t bias_bytes = (1024 + 4) * sizeof(float);
    if (ws_size < B_bytes + bias_bytes) {
        sentinel_kernel<<<(out_size + 255) / 256, 256, 0, stream>>>(out, out_size);
        return;
    }

    char*  Bt    = (char*)d_ws;
    float* biasT = (float*)((char*)d_ws + B_bytes);

    bias_thresh_kernel<<<256, 256, 0, stream>>>(sw, grid, biasT);
    pack_B_kernel<<<512, 256, 0, stream>>>(sw, bw, Bt);
    gemm_kernel<<<512, 256, 0, stream>>>(x, Bt, biasT, out);
}